// Round 6
// baseline (253.100 us; speedup 1.0000x reference)
//
#include <hip/hip_runtime.h>
#include <hip/hip_bf16.h>

// Problem constants
constexpr int B_  = 2;
constexpr int L_  = 1024;
constexpr int DIN = 1024;
constexpr int DM  = 2048;
constexpr int DS  = 16;
constexpr int DR  = 128;
constexpr int KC  = 4;       // conv kernel size
constexpr int M_  = B_ * L_; // 2048 rows
constexpr int NP2 = 256;     // packed projection width (16+16+128 padded to 256)
constexpr int NPC = 160;     // compact packed width (16+16+128)
constexpr int KSLICES = 8;   // split-K for proj GEMM (K slice = 256)
constexpr int KSL = DM / KSLICES;     // 256

// Chunked scan parameters
constexpr int NC = 32;               // number of chunks
constexpr int CL = L_ / NC;          // chunk length (32)
constexpr int S_ = B_ * DM * DS;     // 65536 scan states

typedef __bf16 bf16x8 __attribute__((ext_vector_type(8)));
typedef float  f32x4  __attribute__((ext_vector_type(4)));

// ---------------------------------------------------------------------------
// async global->LDS 16B copy (global_load_lds_dwordx4).
// LDS dest must be wave-uniform base; HW adds lane*16.
// ---------------------------------------------------------------------------
__device__ __forceinline__ void gload_lds16(const void* g, void* l) {
    __builtin_amdgcn_global_load_lds(
        (const __attribute__((address_space(1))) void*)g,
        (__attribute__((address_space(3))) void*)l, 16, 0, 0);
}

// ---------------------------------------------------------------------------
// Fused operand prep (one launch): convert + 4 transposes + proj pack +
// conv-weight transpose.
// ---------------------------------------------------------------------------
__device__ __forceinline__ void transpose_block(const float* __restrict__ in,
                                                __bf16* __restrict__ out,
                                                int R, int C, int bx, int by, int t) {
    __shared__ float tile[32][33];
    int tx = t & 31, ty = t >> 5;   // (32, 8)
    #pragma unroll
    for (int j = 0; j < 32; j += 8)
        tile[ty + j][tx] = in[(size_t)(by * 32 + ty + j) * C + (bx * 32 + tx)];
    __syncthreads();
    #pragma unroll
    for (int j = 0; j < 32; j += 8)
        out[(size_t)(bx * 32 + ty + j) * R + (by * 32 + tx)] = (__bf16)tile[tx][ty + j];
}

__global__ void prep_all(const float* __restrict__ x_in, const float* __restrict__ W_in,
                         const float* __restrict__ W_res, const float* __restrict__ W_out,
                         const float* __restrict__ dt_w,
                         const float* __restrict__ W_B, const float* __restrict__ W_C,
                         const float* __restrict__ W_dt, const float* __restrict__ conv_w,
                         __bf16* __restrict__ xinB, __bf16* __restrict__ WinT,
                         __bf16* __restrict__ WresT, __bf16* __restrict__ WoutT,
                         __bf16* __restrict__ dtwT, __bf16* __restrict__ projW,
                         float* __restrict__ cwT) {
    int blk = blockIdx.x, t = threadIdx.x;
    if (blk < 8192) {
        int i = blk * 256 + t;
        xinB[i] = (__bf16)x_in[i];
    } else if (blk < 10240) {
        int b = blk - 8192;                       // grid (64, 32)
        transpose_block(W_in, WinT, DIN, DM, b % 64, b / 64, t);
    } else if (blk < 12288) {
        int b = blk - 10240;
        transpose_block(W_res, WresT, DIN, DM, b % 64, b / 64, t);
    } else if (blk < 14336) {
        int b = blk - 12288;                      // grid (32, 64)
        transpose_block(W_out, WoutT, DM, DIN, b % 32, b / 32, t);
    } else if (blk < 14592) {
        int b = blk - 14336;                      // grid (64, 4)
        transpose_block(dt_w, dtwT, DR, DM, b % 64, b / 64, t);
    } else if (blk < 16640) {
        int i = (blk - 14592) * 256 + t;          // 0 .. NP2*DM
        int k = i % DM;
        int n = i / DM;
        float v = 0.f;
        if (n < 16)        v = W_B[(size_t)k * DS + n];
        else if (n < 32)   v = W_C[(size_t)k * DS + (n - 16)];
        else if (n < 160)  v = W_dt[(size_t)k * DR + (n - 32)];
        projW[i] = (__bf16)v;
    } else {
        int j = (blk - 16640) * 256 + t;          // 0 .. KC*DM
        int tap = j / DM, d = j % DM;
        cwT[j] = conv_w[d * KC + tap];
    }
}

// ---------------------------------------------------------------------------
// Reduce proj split-K bf16 partials (dense stride NPC) and route:
// Bp, Cp (f32), dtmp (bf16). Fully coalesced.
// ---------------------------------------------------------------------------
__global__ void reduce_split(const __bf16* __restrict__ PpartB, float* __restrict__ Bp,
                             float* __restrict__ Cp, __bf16* __restrict__ dtmpB) {
    int i = blockIdx.x * 256 + threadIdx.x;   // 0 .. M_*NPC
    int row = i / NPC, c = i % NPC;
    float v = 0.f;
    #pragma unroll
    for (int ks = 0; ks < KSLICES; ks++)
        v += (float)PpartB[(size_t)ks * M_ * NPC + i];
    if (c < 16)       Bp[(size_t)row * DS + c] = v;
    else if (c < 32)  Cp[(size_t)row * DS + (c - 16)] = v;
    else              dtmpB[(size_t)row * DR + (c - 32)] = (__bf16)v;
}

// ---------------------------------------------------------------------------
// Input GEMM (x|res): block tile 128(M) x 256(N), 8 waves 2Mx4N of 64x64
// wave tiles. Rationale (R5 post-mortem): 64x32 wave tiles need 768 B LDS
// per MFMA (~1.8x MFMA time at 85 B/cyc ds_read_b128); 64x64 needs 512 B
// (~1.2x). BK=64 as two proven 32-halves, dbuf 2-phase. 96 KB LDS, grid
// (16,16) = 1 block/CU (512 thr = 8 waves/CU).
// Dual output: col<DM -> Cx, else -> Cres (both bf16, stride DM).
// ---------------------------------------------------------------------------
__global__ void gemm_in(const __bf16* __restrict__ A, const __bf16* __restrict__ BT,
                        __bf16* __restrict__ Cx, __bf16* __restrict__ Cres,
                        int K, int lda, int ldb) {
    __shared__ __bf16 sA[2][2][128 * 32];   // 32 KB
    __shared__ __bf16 sB[2][2][256 * 32];   // 64 KB
    int t = threadIdx.x;
    int lane = t & 63, w = t >> 6;
    int wm = w >> 2, wn = w & 3;            // 2(M) x 4(N), 64x64 each
    int m0 = blockIdx.y * 128, n0 = blockIdx.x * 256;
    int q = lane >> 4, rr = lane & 15;

    f32x4 acc[4][4] = {};
    int srow = t >> 2;          // 0..127
    int slot = t & 3;

    const int nt = K >> 6;

    // per half: A = 1 gload/thread (128 rows), B = 2 rounds (256 rows)
    auto stage = [&](int kt, int bufi) {
        int gkbA = slot ^ ((srow >> 1) & 3);
        #pragma unroll
        for (int s = 0; s < 2; s++) {
            gload_lds16(A + (size_t)(m0 + srow) * lda + kt + s * 32 + gkbA * 8,
                        &sA[bufi][s][w * 512]);
            #pragma unroll
            for (int rnd = 0; rnd < 2; rnd++) {
                int row = srow + rnd * 128;
                int gkb = slot ^ ((row >> 1) & 3);
                gload_lds16(BT + (size_t)(n0 + row) * ldb + kt + s * 32 + gkb * 8,
                            &sB[bufi][s][rnd * 4096 + w * 512]);
            }
        }
    };

    stage(0, 0);
    __syncthreads();

    int cur = 0;
    for (int tix = 0; tix < nt; tix++) {
        if (tix + 1 < nt) stage((tix + 1) << 6, cur ^ 1);

        #pragma unroll
        for (int s = 0; s < 2; s++) {
            bf16x8 af[4], bfr[4];
            #pragma unroll
            for (int i = 0; i < 4; i++) {
                int rowA = wm * 64 + i * 16 + rr;
                af[i] = *(const bf16x8*)(&sA[cur][s][rowA * 32 + ((q ^ ((rowA >> 1) & 3)) * 8)]);
            }
            #pragma unroll
            for (int j = 0; j < 4; j++) {
                int rowB = wn * 64 + j * 16 + rr;
                bfr[j] = *(const bf16x8*)(&sB[cur][s][rowB * 32 + ((q ^ ((rowB >> 1) & 3)) * 8)]);
            }
            #pragma unroll
            for (int i = 0; i < 4; i++)
                #pragma unroll
                for (int j = 0; j < 4; j++)
                    acc[i][j] = __builtin_amdgcn_mfma_f32_16x16x32_bf16(af[i], bfr[j], acc[i][j], 0, 0, 0);
        }

        __syncthreads();
        cur ^= 1;
    }

    #pragma unroll
    for (int i = 0; i < 4; i++) {
        #pragma unroll
        for (int j = 0; j < 4; j++) {
            int col = n0 + wn * 64 + j * 16 + rr;
            #pragma unroll
            for (int jj = 0; jj < 4; jj++) {
                int row = m0 + wm * 64 + i * 16 + q * 4 + jj;
                float v = acc[i][j][jj];
                if (col < DM) Cx[(size_t)row * DM + col] = (__bf16)v;
                else          Cres[(size_t)row * DM + (col - DM)] = (__bf16)v;
            }
        }
    }
}

// ---------------------------------------------------------------------------
// MFMA GEMM (proj/delta): 128x128 block tile, 8 waves 2Mx4N of 64x32, BK=64
// as two 32-halves, dbuf 2-phase (R5 config — these GEMMs are small-K,
// prologue-dominated; left unchanged).
// EPI: 1 = +bias[col], softplus -> bf16 Cb (stride N);
//      4 = compact bf16 partial: col<NPC -> Cb + z*M*NPC, stride NPC.
// ---------------------------------------------------------------------------
template<int EPI>
__global__ void gemm_tile128(const __bf16* __restrict__ A, const __bf16* __restrict__ BT,
                             float* __restrict__ Cf, __bf16* __restrict__ Cb,
                             const float* __restrict__ bias, int M, int N, int K,
                             int lda, int ldb) {
    __shared__ __bf16 sA[2][2][128 * 32];
    __shared__ __bf16 sB[2][2][128 * 32];
    int t = threadIdx.x;
    int lane = t & 63, w = t >> 6;
    int wm = w >> 2, wn = w & 3;
    int m0 = blockIdx.y * 128, n0 = blockIdx.x * 128;
    int kbase = blockIdx.z * K;
    int q = lane >> 4, rr = lane & 15;

    f32x4 acc[4][2] = {};
    int srow = t >> 2;
    int slot = t & 3;

    const int nt = K >> 6;

    auto stage = [&](int kt, int bufi) {
        int gkb = slot ^ ((srow >> 1) & 3);
        #pragma unroll
        for (int s = 0; s < 2; s++) {
            gload_lds16(A  + (size_t)(m0 + srow) * lda + kbase + kt + s * 32 + gkb * 8,
                        &sA[bufi][s][w * 512]);
            gload_lds16(BT + (size_t)(n0 + srow) * ldb + kbase + kt + s * 32 + gkb * 8,
                        &sB[bufi][s][w * 512]);
        }
    };

    stage(0, 0);
    __syncthreads();

    int cur = 0;
    for (int tix = 0; tix < nt; tix++) {
        if (tix + 1 < nt) stage((tix + 1) << 6, cur ^ 1);

        #pragma unroll
        for (int s = 0; s < 2; s++) {
            bf16x8 af[4], bfr[2];
            #pragma unroll
            for (int i = 0; i < 4; i++) {
                int rowA = wm * 64 + i * 16 + rr;
                af[i] = *(const bf16x8*)(&sA[cur][s][rowA * 32 + ((q ^ ((rowA >> 1) & 3)) * 8)]);
            }
            #pragma unroll
            for (int j = 0; j < 2; j++) {
                int rowB = wn * 32 + j * 16 + rr;
                bfr[j] = *(const bf16x8*)(&sB[cur][s][rowB * 32 + ((q ^ ((rowB >> 1) & 3)) * 8)]);
            }
            #pragma unroll
            for (int i = 0; i < 4; i++)
                #pragma unroll
                for (int j = 0; j < 2; j++)
                    acc[i][j] = __builtin_amdgcn_mfma_f32_16x16x32_bf16(af[i], bfr[j], acc[i][j], 0, 0, 0);
        }

        __syncthreads();
        cur ^= 1;
    }

    #pragma unroll
    for (int i = 0; i < 4; i++) {
        #pragma unroll
        for (int j = 0; j < 2; j++) {
            int col = n0 + wn * 32 + j * 16 + rr;
            #pragma unroll
            for (int jj = 0; jj < 4; jj++) {
                int row = m0 + wm * 64 + i * 16 + q * 4 + jj;
                float v = acc[i][j][jj];
                if (EPI == 1) {
                    float z = v + bias[col];
                    Cb[(size_t)row * N + col] = (__bf16)((z > 20.f) ? z : log1pf(__expf(z)));
                } else {
                    if (col < NPC)
                        Cb[(size_t)blockIdx.z * M * NPC + (size_t)row * NPC + col] = (__bf16)v;
                }
            }
        }
    }
}

// ---------------------------------------------------------------------------
// Out GEMM: 128(M)x64(N) tile, 8 waves = 2 M-positions (64 rows) x K-split-4.
// Each wave: 64x64 wave tile over its K-quarter (512 B LDS/MFMA vs R5's
// 1.5 KB at 32x32 tiles). Macro K-step 128 = 4 x BK32 ksubs; wave kg
// computes ksub kg. LDS-tree reduction over kg in epilogue. 96 KB LDS.
// ---------------------------------------------------------------------------
__global__ void gemm_out64(const __bf16* __restrict__ A, const __bf16* __restrict__ BT,
                           float* __restrict__ C, int M, int N, int K, int lda, int ldb) {
    __shared__ __bf16 sA[2][4][128 * 32];   // 64 KB
    __shared__ __bf16 sB[2][4][64 * 32];    // 32 KB
    int t = threadIdx.x;
    int lane = t & 63, w = t >> 6;
    int pos = w & 1, kg = w >> 1;           // M-position, K-group
    int m0 = blockIdx.y * 128, n0 = blockIdx.x * 64;
    int q = lane >> 4, rr = lane & 15;

    f32x4 acc[4][4] = {};
    int srow = t >> 2;          // 0..127
    int slot = t & 3;

    const int nt = K >> 7;      // macro K-step 128

    auto stage = [&](int kt, int bufi) {
        int gkb = slot ^ ((srow >> 1) & 3);
        #pragma unroll
        for (int s = 0; s < 4; s++) {
            gload_lds16(A + (size_t)(m0 + srow) * lda + kt + s * 32 + gkb * 8,
                        &sA[bufi][s][w * 512]);
            if (t < 256)    // waves 0-3 stage B (64 rows); wave-uniform branch
                gload_lds16(BT + (size_t)(n0 + srow) * ldb + kt + s * 32 + gkb * 8,
                            &sB[bufi][s][w * 512]);
        }
    };

    stage(0, 0);
    __syncthreads();

    int cur = 0;
    for (int tix = 0; tix < nt; tix++) {
        if (tix + 1 < nt) stage((tix + 1) << 7, cur ^ 1);

        bf16x8 af[4], bfr[4];
        #pragma unroll
        for (int i = 0; i < 4; i++) {
            int rowA = pos * 64 + i * 16 + rr;
            af[i] = *(const bf16x8*)(&sA[cur][kg][rowA * 32 + ((q ^ ((rowA >> 1) & 3)) * 8)]);
        }
        #pragma unroll
        for (int j = 0; j < 4; j++) {
            int rowB = j * 16 + rr;
            bfr[j] = *(const bf16x8*)(&sB[cur][kg][rowB * 32 + ((q ^ ((rowB >> 1) & 3)) * 8)]);
        }
        #pragma unroll
        for (int i = 0; i < 4; i++)
            #pragma unroll
            for (int j = 0; j < 4; j++)
                acc[i][j] = __builtin_amdgcn_mfma_f32_16x16x32_bf16(af[i], bfr[j], acc[i][j], 0, 0, 0);

        __syncthreads();
        cur ^= 1;
    }

    // ---- cross-kg reduction via LDS (reuse sA: 16384 f32 = 64 KB exactly) ----
    float* red = (float*)sA;
    if (kg >= 2) {              // stage 1 writers: kg2 -> slot 0, kg3 -> slot 1
        int base = ((pos * 2 + (kg - 2)) * 64 + lane) * 64;
        #pragma unroll
        for (int i = 0; i < 4; i++)
            #pragma unroll
            for (int j = 0; j < 4; j++)
                #pragma unroll
                for (int jj = 0; jj < 4; jj++)
                    red[base + (i * 4 + j) * 4 + jj] = acc[i][j][jj];
    }
    __syncthreads();
    if (kg < 2) {               // kg0 += slot0 (kg2), kg1 += slot1 (kg3)
        int base = ((pos * 2 + kg) * 64 + lane) * 64;
        #pragma unroll
        for (int i = 0; i < 4; i++)
            #pragma unroll
            for (int j = 0; j < 4; j++)
                #pragma unroll
                for (int jj = 0; jj < 4; jj++)
                    acc[i][j][jj] += red[base + (i * 4 + j) * 4 + jj];
    }
    __syncthreads();
    if (kg == 1) {              // stage 2 writer: kg1 -> slot 0
        int base = ((pos * 2) * 64 + lane) * 64;
        #pragma unroll
        for (int i = 0; i < 4; i++)
            #pragma unroll
            for (int j = 0; j < 4; j++)
                #pragma unroll
                for (int jj = 0; jj < 4; jj++)
                    red[base + (i * 4 + j) * 4 + jj] = acc[i][j][jj];
    }
    __syncthreads();
    if (kg == 0) {              // final sum + store
        int base = ((pos * 2) * 64 + lane) * 64;
        #pragma unroll
        for (int i = 0; i < 4; i++) {
            #pragma unroll
            for (int j = 0; j < 4; j++) {
                int col = n0 + j * 16 + rr;
                #pragma unroll
                for (int jj = 0; jj < 4; jj++) {
                    float v = acc[i][j][jj] + red[base + (i * 4 + j) * 4 + jj];
                    int row = m0 + pos * 64 + i * 16 + q * 4 + jj;
                    C[(size_t)row * N + col] = v;
                }
            }
        }
    }
}

// ---------------------------------------------------------------------------
// Causal depthwise conv (K=4) + bias + SiLU, vectorized.
// ---------------------------------------------------------------------------
__global__ void conv_silu(const __bf16* __restrict__ x, const float* __restrict__ cwT,
                          const float* __restrict__ bias, __bf16* __restrict__ xcB) {
    int row = blockIdx.x;          // 0..M_-1
    int d   = threadIdx.x * 8;     // 0..DM-8
    int l   = row % L_;
    size_t base = (size_t)row * DM + d;

    float acc[8];
    {
        const f32x4* b4 = (const f32x4*)(bias + d);
        f32x4 b0 = b4[0], b1 = b4[1];
        #pragma unroll
        for (int q = 0; q < 4; q++) { acc[q] = b0[q]; acc[4 + q] = b1[q]; }
    }
    #pragma unroll
    for (int i = 0; i < KC; i++) {
        int li = l - (KC - 1) + i;
        if (li >= 0) {                       // uniform across block
            bf16x8 xv = *(const bf16x8*)(x + base + (size_t)(i - (KC - 1)) * DM);
            const f32x4* w4 = (const f32x4*)(cwT + (size_t)i * DM + d);
            f32x4 w0 = w4[0], w1 = w4[1];
            #pragma unroll
            for (int q = 0; q < 4; q++) {
                acc[q]     = fmaf((float)xv[q],     w0[q], acc[q]);
                acc[4 + q] = fmaf((float)xv[4 + q], w1[q], acc[4 + q]);
            }
        }
    }
    bf16x8 out;
    #pragma unroll
    for (int q = 0; q < 8; q++) {
        float v = acc[q] / (1.f + __expf(-acc[q]));
        out[q] = (__bf16)v;
    }
    *(bf16x8*)(xcB + base) = out;
}

// ---------------------------------------------------------------------------
// Chunked scan, phase 1. Thread owns one (b, dm, chunk): 16 ds states in regs.
// ---------------------------------------------------------------------------
__global__ void scan_phase1(const __bf16* __restrict__ delta, const __bf16* __restrict__ xc,
                            const float* __restrict__ Bp, const float* __restrict__ A_log,
                            __bf16* __restrict__ aprodB, __bf16* __restrict__ cendB) {
    int blk = blockIdx.x;
    int c   = blk % NC;
    int rem = blk / NC;
    int dmt = rem % (DM / 256);
    int b   = rem / (DM / 256);
    int t   = threadIdx.x;
    int dm  = dmt * 256 + t;
    int l0  = c * CL;

    __shared__ float sB[CL * DS];      // 2 KB
    sB[t]       = Bp[((size_t)b * L_ + l0) * DS + t];
    sB[t + 256] = Bp[((size_t)b * L_ + l0) * DS + t + 256];
    __syncthreads();

    float Aval[DS];
    {
        const f32x4* Ap = (const f32x4*)(A_log + (size_t)dm * DS);
        #pragma unroll
        for (int r4 = 0; r4 < 4; r4++) {
            f32x4 a = Ap[r4];
            #pragma unroll
            for (int q = 0; q < 4; q++) Aval[r4 * 4 + q] = -__expf(a[q]);
        }
    }

    float h[DS], ap[DS];
    #pragma unroll
    for (int i = 0; i < DS; i++) { h[i] = 0.f; ap[i] = 1.f; }

    size_t base = ((size_t)b * L_ + l0) * DM + dm;
    #pragma unroll 4
    for (int j = 0; j < CL; j++) {
        float dl  = (float)delta[base + (size_t)j * DM];
        float xv  = (float)xc[base + (size_t)j * DM];
        float cmn = dl * xv;
        const f32x4* sB4 = (const f32x4*)(sB + j * DS);
        #pragma unroll
        for (int r4 = 0; r4 < 4; r4++) {
            f32x4 bv = sB4[r4];
            #pragma unroll
            for (int q = 0; q < 4; q++) {
                int i = r4 * 4 + q;
                float dA = __expf(dl * Aval[i]);
                ap[i] *= dA;
                h[i] = fmaf(dA, h[i], cmn * bv[q]);
            }
        }
    }

    size_t s = ((size_t)(b * DM + dm)) * DS;
    #pragma unroll
    for (int r8 = 0; r8 < 2; r8++) {
        bf16x8 va, vh;
        #pragma unroll
        for (int q = 0; q < 8; q++) { va[q] = (__bf16)ap[r8 * 8 + q]; vh[q] = (__bf16)h[r8 * 8 + q]; }
        ((bf16x8*)(aprodB + (size_t)c * S_ + s))[r8] = va;
        ((bf16x8*)(cendB  + (size_t)c * S_ + s))[r8] = vh;
    }
}

// ---------------------------------------------------------------------------
// Chunked scan, phase 2: scan chunk summaries (bf16 in/out, f32 math).
// One thread per state: 65536 threads = 1024 waves; fully coalesced.
// ---------------------------------------------------------------------------
__global__ void scan_phase2(const __bf16* __restrict__ aprodB, const __bf16* __restrict__ cendB,
                            __bf16* __restrict__ hinitB) {
    int u = blockIdx.x * 256 + threadIdx.x;   // 0..S_-1
    float h = 0.f;
    #pragma unroll
    for (int c = 0; c < NC; c++) {
        float a  = (float)aprodB[(size_t)c * S_ + u];
        float ce = (float)cendB [(size_t)c * S_ + u];
        hinitB[(size_t)c * S_ + u] = (__bf16)h;
        h = fmaf(a, h, ce);
    }
}

// ---------------------------------------------------------------------------
// Chunked scan, phase 3: replay from h_init, fused epilogue -> bf16.
// ---------------------------------------------------------------------------
__global__ void scan_phase3(const __bf16* __restrict__ delta, const __bf16* __restrict__ xc,
                            const float* __restrict__ Bp, const float* __restrict__ Cp,
                            const __bf16* __restrict__ res, const float* __restrict__ A_log,
                            const float* __restrict__ Dw, const __bf16* __restrict__ hinitB,
                            __bf16* __restrict__ ybar) {
    int blk = blockIdx.x;
    int c   = blk % NC;
    int rem = blk / NC;
    int dmt = rem % (DM / 256);
    int b   = rem / (DM / 256);
    int t   = threadIdx.x;
    int dm  = dmt * 256 + t;
    int l0  = c * CL;

    __shared__ float sB[CL * DS];      // 2 KB
    __shared__ float sC[CL * DS];      // 2 KB
    sB[t]       = Bp[((size_t)b * L_ + l0) * DS + t];
    sB[t + 256] = Bp[((size_t)b * L_ + l0) * DS + t + 256];
    sC[t]       = Cp[((size_t)b * L_ + l0) * DS + t];
    sC[t + 256] = Cp[((size_t)b * L_ + l0) * DS + t + 256];
    __syncthreads();

    float Aval[DS];
    {
        const f32x4* Ap = (const f32x4*)(A_log + (size_t)dm * DS);
        #pragma unroll
        for (int r4 = 0; r4 < 4; r4++) {
            f32x4 a = Ap[r4];
            #pragma unroll
            for (int q = 0; q < 4; q++) Aval[r4 * 4 + q] = -__expf(a[q]);
        }
    }
    float Dval = Dw[dm];

    float h[DS];
    {
        size_t s = ((size_t)(b * DM + dm)) * DS;
        #pragma unroll
        for (int r8 = 0; r8 < 2; r8++) {
            bf16x8 v = ((const bf16x8*)(hinitB + (size_t)c * S_ + s))[r8];
            #pragma unroll
            for (int q = 0; q < 8; q++) h[r8 * 8 + q] = (float)v[q];
        }
    }

    size_t base = ((size_t)b * L_ + l0) * DM + dm;
    #pragma unroll 4
    for (int j = 0; j < CL; j++) {
        float dl  = (float)delta[base + (size_t)j * DM];
        float xv  = (float)xc[base + (size_t)j * DM];
        float rv  = (float)res[base + (size_t)j * DM];
        float cmn = dl * xv;
        float y = 0.f;
        const f32x4* sB4 = (const f32x4*)(sB + j * DS);
        const f32x4* sC4 = (const f32x4*)(sC + j * DS);
        #pragma unroll
        for (int r4 = 0; r4 < 4; r4++) {
            f32x4 bv = sB4[r4];
            f32x4 cv = sC4[r4];
            #pragma unroll
            for (int q = 0; q < 4; q++) {
                int i = r4 * 4 + q;
                float dA = __expf(dl * Aval[i]);
                h[i] = fmaf(dA, h[i], cmn * bv[q]);
                y = fmaf(h[i], cv[q], y);
            }
        }
        float g = rv / (1.f + __expf(-rv));
        ybar[base + (size_t)j * DM] = (__bf16)((y + Dval * xv) * g);
    }
}

// ---------------------------------------------------------------------------
extern "C" void kernel_launch(void* const* d_in, const int* in_sizes, int n_in,
                              void* d_out, int out_size, void* d_ws, size_t ws_size,
                              hipStream_t stream) {
    // All reference tensors are float32.
    const float* x_in   = (const float*)d_in[0];
    const float* W_in   = (const float*)d_in[1];
    const float* W_res  = (const float*)d_in[2];
    const float* W_out  = (const float*)d_in[3];
    const float* conv_w = (const float*)d_in[4];
    const float* conv_b = (const float*)d_in[5];
    const float* A_log  = (const float*)d_in[6];
    const float* Dw     = (const float*)d_in[7];
    const float* W_B    = (const float*)d_in[8];
    const float* W_C    = (const float*)d_in[9];
    const float* W_dt   = (const float*)d_in[10];
    const float* dt_w   = (const float*)d_in[11];
    const float* dt_b   = (const float*)d_in[12];

    // ---------------- Workspace layout ----------------
    float* ws_f = (float*)d_ws;
    float* Bp    = ws_f;                        // M_*DS f32
    float* Cp    = Bp + (size_t)M_ * DS;        // M_*DS f32
    float* cwT   = Cp + (size_t)M_ * DS;        // KC*DM f32
    __bf16* bf_base = (__bf16*)(cwT + (size_t)KC * DM);
    __bf16* ybar   = bf_base;                   // M_*DM
    __bf16* xinB   = ybar   + (size_t)M_ * DM;  // M_*DIN
    __bf16* WinT   = xinB   + (size_t)M_ * DIN; // DM*DIN } adjacent: fused (4096 x DIN) BT
    __bf16* WresT  = WinT   + (size_t)DM * DIN; // DM*DIN }
    __bf16* WoutT  = WresT  + (size_t)DM * DIN; // DIN*DM
    __bf16* xB     = WoutT  + (size_t)DIN * DM; // M_*DM (conv input, bf16)
    __bf16* xcB    = xB     + (size_t)M_ * DM;  // M_*DM
    __bf16* projW  = xcB    + (size_t)M_ * DM;  // NP2*DM
    __bf16* dtwT   = projW  + (size_t)NP2 * DM; // DM*DR
    __bf16* dtmpB  = dtwT   + (size_t)DM * DR;  // M_*DR
    __bf16* deltaB = dtmpB  + (size_t)M_ * DR;  // M_*DM
    __bf16* resB   = deltaB + (size_t)M_ * DM;  // M_*DM
    __bf16* aprodB = resB   + (size_t)M_ * DM;  // NC*S_
    __bf16* cendB  = aprodB + (size_t)NC * S_;  // NC*S_
    __bf16* hinitB = cendB  + (size_t)NC * S_;  // NC*S_
    __bf16* PpartB = hinitB + (size_t)NC * S_;  // KSLICES*M_*NPC (compact bf16 partials)

    // ---------------- fused operand prep (1 launch) ----------------
    prep_all<<<16672, 256, 0, stream>>>(x_in, W_in, W_res, W_out, dt_w, W_B, W_C, W_dt,
                                        conv_w, xinB, WinT, WresT, WoutT, dtwT, projW, cwT);

    // Fused input GEMMs: [x (bf16) | res (bf16)] = x_in @ [W_in | W_res]
    gemm_in<<<dim3((2 * DM) / 256, M_ / 128), 512, 0, stream>>>(
        xinB, WinT, xB, resB, DIN, DIN, DIN);

    conv_silu<<<M_, 256, 0, stream>>>(xB, cwT, conv_b, xcB);

    // Packed projections, split-K -> compact bf16 partials (stride NPC)
    gemm_tile128<4><<<dim3(NP2 / 128, M_ / 128, KSLICES), 512, 0, stream>>>(
        xcB, projW, nullptr, PpartB, nullptr, M_, NP2, KSL, DM, DM);
    reduce_split<<<(M_ * NPC) / 256, 256, 0, stream>>>(PpartB, Bp, Cp, dtmpB);

    // delta = softplus(dtmp @ dt_w + dt_b) -> bf16  (M_ x DM, K=DR)
    gemm_tile128<1><<<dim3(DM / 128, M_ / 128, 1), 512, 0, stream>>>(
        dtmpB, dtwT, nullptr, deltaB, dt_b, M_, DM, DR, DR, DR);

    // Chunked selective scan (3 launches; kernel boundary = cheap barrier)
    int nblk = B_ * (DM / 256) * NC;   // 512
    scan_phase1<<<nblk, 256, 0, stream>>>(deltaB, xcB, Bp, A_log, aprodB, cendB);
    scan_phase2<<<S_ / 256, 256, 0, stream>>>(aprodB, cendB, hinitB);
    scan_phase3<<<nblk, 256, 0, stream>>>(deltaB, xcB, Bp, Cp, resB, A_log, Dw, hinitB, ybar);

    // out = ybar @ W_out  (M_ x DIN, K=DM), k-split-4 waves, f32 store
    gemm_out64<<<dim3(DIN / 64, M_ / 128), 512, 0, stream>>>(
        ybar, WoutT, (float*)d_out, M_, DIN, DM, DM, DM);
}

// Round 7
// 245.415 us; speedup vs baseline: 1.0313x; 1.0313x over previous
//
#include <hip/hip_runtime.h>
#include <hip/hip_bf16.h>

// Problem constants
constexpr int B_  = 2;
constexpr int L_  = 1024;
constexpr int DIN = 1024;
constexpr int DM  = 2048;
constexpr int DS  = 16;
constexpr int DR  = 128;
constexpr int KC  = 4;       // conv kernel size
constexpr int M_  = B_ * L_; // 2048 rows
constexpr int NP2 = 256;     // packed projection width (16+16+128 padded to 256)
constexpr int NPC = 160;     // compact packed width (16+16+128)
constexpr int KSLICES = 8;   // split-K for proj GEMM (K slice = 256)
constexpr int KSL = DM / KSLICES;     // 256

// Chunked scan parameters
constexpr int NC = 32;               // number of chunks
constexpr int CL = L_ / NC;          // chunk length (32)
constexpr int S_ = B_ * DM * DS;     // 65536 scan states

typedef __bf16 bf16x8 __attribute__((ext_vector_type(8)));
typedef float  f32x4  __attribute__((ext_vector_type(4)));

// ---------------------------------------------------------------------------
// async global->LDS 16B copy (global_load_lds_dwordx4).
// LDS dest must be wave-uniform base; HW adds lane*16.
// ---------------------------------------------------------------------------
__device__ __forceinline__ void gload_lds16(const void* g, void* l) {
    __builtin_amdgcn_global_load_lds(
        (const __attribute__((address_space(1))) void*)g,
        (__attribute__((address_space(3))) void*)l, 16, 0, 0);
}

// ---------------------------------------------------------------------------
// Fused operand prep (one launch): convert + 4 transposes + proj pack +
// conv-weight transpose + d_out zero (for gemm_out K-split atomics).
// ---------------------------------------------------------------------------
__device__ __forceinline__ void transpose_block(const float* __restrict__ in,
                                                __bf16* __restrict__ out,
                                                int R, int C, int bx, int by, int t) {
    __shared__ float tile[32][33];
    int tx = t & 31, ty = t >> 5;   // (32, 8)
    #pragma unroll
    for (int j = 0; j < 32; j += 8)
        tile[ty + j][tx] = in[(size_t)(by * 32 + ty + j) * C + (bx * 32 + tx)];
    __syncthreads();
    #pragma unroll
    for (int j = 0; j < 32; j += 8)
        out[(size_t)(bx * 32 + ty + j) * R + (by * 32 + tx)] = (__bf16)tile[tx][ty + j];
}

__global__ void prep_all(const float* __restrict__ x_in, const float* __restrict__ W_in,
                         const float* __restrict__ W_res, const float* __restrict__ W_out,
                         const float* __restrict__ dt_w,
                         const float* __restrict__ W_B, const float* __restrict__ W_C,
                         const float* __restrict__ W_dt, const float* __restrict__ conv_w,
                         __bf16* __restrict__ xinB, __bf16* __restrict__ WinT,
                         __bf16* __restrict__ WresT, __bf16* __restrict__ WoutT,
                         __bf16* __restrict__ dtwT, __bf16* __restrict__ projW,
                         float* __restrict__ cwT, float* __restrict__ outz) {
    int blk = blockIdx.x, t = threadIdx.x;
    if (blk < 8192) {
        int i = blk * 256 + t;
        xinB[i] = (__bf16)x_in[i];
    } else if (blk < 10240) {
        int b = blk - 8192;                       // grid (64, 32)
        transpose_block(W_in, WinT, DIN, DM, b % 64, b / 64, t);
    } else if (blk < 12288) {
        int b = blk - 10240;
        transpose_block(W_res, WresT, DIN, DM, b % 64, b / 64, t);
    } else if (blk < 14336) {
        int b = blk - 12288;                      // grid (32, 64)
        transpose_block(W_out, WoutT, DM, DIN, b % 32, b / 32, t);
    } else if (blk < 14592) {
        int b = blk - 14336;                      // grid (64, 4)
        transpose_block(dt_w, dtwT, DR, DM, b % 64, b / 64, t);
    } else if (blk < 16640) {
        int i = (blk - 14592) * 256 + t;          // 0 .. NP2*DM
        int k = i % DM;
        int n = i / DM;
        float v = 0.f;
        if (n < 16)        v = W_B[(size_t)k * DS + n];
        else if (n < 32)   v = W_C[(size_t)k * DS + (n - 16)];
        else if (n < 160)  v = W_dt[(size_t)k * DR + (n - 32)];
        projW[i] = (__bf16)v;
    } else if (blk < 16672) {
        int j = (blk - 16640) * 256 + t;          // 0 .. KC*DM
        int tap = j / DM, d = j % DM;
        cwT[j] = conv_w[d * KC + tap];
    } else {
        // zero d_out (M_*DIN f32) for the K-split atomic out-GEMM
        int i = (blk - 16672) * 256 + t;          // 0 .. M_*DIN/4
        ((f32x4*)outz)[i] = f32x4{0.f, 0.f, 0.f, 0.f};
    }
}

// ---------------------------------------------------------------------------
// Reduce proj split-K bf16 partials (dense stride NPC) and route:
// Bp, Cp (f32), dtmp (bf16). Fully coalesced.
// ---------------------------------------------------------------------------
__global__ void reduce_split(const __bf16* __restrict__ PpartB, float* __restrict__ Bp,
                             float* __restrict__ Cp, __bf16* __restrict__ dtmpB) {
    int i = blockIdx.x * 256 + threadIdx.x;   // 0 .. M_*NPC
    int row = i / NPC, c = i % NPC;
    float v = 0.f;
    #pragma unroll
    for (int ks = 0; ks < KSLICES; ks++)
        v += (float)PpartB[(size_t)ks * M_ * NPC + i];
    if (c < 16)       Bp[(size_t)row * DS + c] = v;
    else if (c < 32)  Cp[(size_t)row * DS + (c - 16)] = v;
    else              dtmpB[(size_t)row * DR + (c - 32)] = (__bf16)v;
}

// ---------------------------------------------------------------------------
// MFMA GEMM: 128x128 block tile, BK=64 as two proven 32-halves, dbuf 2-phase.
// THIS ROUND: 1024 threads = 16 WAVES per block (wave grid 4x4, 32x32 wave
// tiles). Only lever that has moved this pipeline is waves/CU (R3->R4 +14us,
// R5->R6 regression when halved): gemm<2> now 2 blk/CU x 16w = 32 waves/CU;
// proj/delta 16 waves/CU. Staging: waves 0-7 stage A, 8-15 stage B (one 16B
// chunk per thread per half); same 0-conflict XOR swizzle.
// EPI: 1 = +bias[col], softplus -> bf16 Cb (stride N);
//      2 = dual-output bf16: col<DM -> (bf16*)Cf (x), else -> Cb (res), stride DM;
//      4 = compact bf16 partial: col<NPC -> Cb + z*M*NPC, stride NPC.
// ---------------------------------------------------------------------------
template<int EPI>
__global__ __launch_bounds__(1024, 8)
void gemm_tile128(const __bf16* __restrict__ A, const __bf16* __restrict__ BT,
                  float* __restrict__ Cf, __bf16* __restrict__ Cb,
                  const float* __restrict__ bias, int M, int N, int K,
                  int lda, int ldb) {
    __shared__ __bf16 sA[2][2][128 * 32];   // 16 KB
    __shared__ __bf16 sB[2][2][128 * 32];   // 16 KB
    int t = threadIdx.x;
    int lane = t & 63, w = t >> 6;          // 16 waves
    int wm = w >> 2, wn = w & 3;            // 4(M) x 4(N): 32x32 each
    int m0 = blockIdx.y * 128, n0 = blockIdx.x * 128;
    int kbase = blockIdx.z * K;
    int q = lane >> 4, rr = lane & 15;

    f32x4 acc[2][2] = {};

    const int nt = K >> 6;

    // staging: t<512 -> A rows 0..127, else B rows 0..127; 2 halves each.
    int t2 = t & 511;
    int srow = t2 >> 2;         // 0..127
    int slot = t2 & 3;
    int gkb = slot ^ ((srow >> 1) & 3);

    auto stage = [&](int kt, int bufi) {
        if (t < 512) {
            #pragma unroll
            for (int s = 0; s < 2; s++)
                gload_lds16(A + (size_t)(m0 + srow) * lda + kbase + kt + s * 32 + gkb * 8,
                            &sA[bufi][s][w * 512]);
        } else {
            #pragma unroll
            for (int s = 0; s < 2; s++)
                gload_lds16(BT + (size_t)(n0 + srow) * ldb + kbase + kt + s * 32 + gkb * 8,
                            &sB[bufi][s][(w - 8) * 512]);
        }
    };

    stage(0, 0);
    __syncthreads();   // tile 0 resident

    int cur = 0;
    for (int tix = 0; tix < nt; tix++) {
        if (tix + 1 < nt) stage((tix + 1) << 6, cur ^ 1);

        #pragma unroll
        for (int s = 0; s < 2; s++) {
            bf16x8 af[2], bfr[2];
            #pragma unroll
            for (int i = 0; i < 2; i++) {
                int rowA = wm * 32 + i * 16 + rr;
                af[i] = *(const bf16x8*)(&sA[cur][s][rowA * 32 + ((q ^ ((rowA >> 1) & 3)) * 8)]);
            }
            #pragma unroll
            for (int j = 0; j < 2; j++) {
                int rowB = wn * 32 + j * 16 + rr;
                bfr[j] = *(const bf16x8*)(&sB[cur][s][rowB * 32 + ((q ^ ((rowB >> 1) & 3)) * 8)]);
            }
            #pragma unroll
            for (int i = 0; i < 2; i++)
                #pragma unroll
                for (int j = 0; j < 2; j++)
                    acc[i][j] = __builtin_amdgcn_mfma_f32_16x16x32_bf16(af[i], bfr[j], acc[i][j], 0, 0, 0);
        }

        __syncthreads();   // drains vmcnt (next tile resident) + lgkm; WAR safe
        cur ^= 1;
    }

    #pragma unroll
    for (int i = 0; i < 2; i++) {
        #pragma unroll
        for (int j = 0; j < 2; j++) {
            int col = n0 + wn * 32 + j * 16 + rr;
            #pragma unroll
            for (int jj = 0; jj < 4; jj++) {
                int row = m0 + wm * 32 + i * 16 + q * 4 + jj;
                float v = acc[i][j][jj];
                if (EPI == 1) {
                    float z = v + bias[col];
                    Cb[(size_t)row * N + col] = (__bf16)((z > 20.f) ? z : log1pf(__expf(z)));
                } else if (EPI == 2) {
                    if (col < DM) ((__bf16*)Cf)[(size_t)row * DM + col] = (__bf16)v;
                    else          Cb[(size_t)row * DM + (col - DM)] = (__bf16)v;
                } else {
                    if (col < NPC)
                        Cb[(size_t)blockIdx.z * M * NPC + (size_t)row * NPC + col] = (__bf16)v;
                }
            }
        }
    }
}

// ---------------------------------------------------------------------------
// Out GEMM: 128(M)x64(N) tile, 8 waves (512 thr) each 32x32 (R5-proven
// internals). THIS ROUND: block-level K-split-2 (blockIdx.z) + f32 atomicAdd
// epilogue (d_out zeroed in prep_all) -> grid 256->512 = 16 waves/CU.
// ---------------------------------------------------------------------------
__global__ void gemm_out64(const __bf16* __restrict__ A, const __bf16* __restrict__ BT,
                           float* __restrict__ C, int M, int N, int K, int lda, int ldb) {
    __shared__ __bf16 sA[2][2][128 * 32];   // 32 KB
    __shared__ __bf16 sB[2][2][64 * 32];    // 16 KB
    int t = threadIdx.x;
    int lane = t & 63, w = t >> 6;        // 8 waves
    int wm = w >> 1, wn = w & 1;          // 4(M) x 2(N): 32x32 each
    int m0 = blockIdx.y * 128, n0 = blockIdx.x * 64;
    int kh = K >> 1;
    int kbase = blockIdx.z * kh;
    int q = lane >> 4, rr = lane & 15;

    f32x4 acc[2][2] = {};
    int srow = t >> 2;          // 0..127
    int slot = t & 3;

    const int nt = kh >> 6;

    auto stage = [&](int kt, int bufi) {
        int gkb = slot ^ ((srow >> 1) & 3);
        #pragma unroll
        for (int s = 0; s < 2; s++) {
            gload_lds16(A + (size_t)(m0 + srow) * lda + kbase + kt + s * 32 + gkb * 8,
                        &sA[bufi][s][w * 512]);
            if (t < 256)   // waves 0-3 stage B (64 rows); wave-uniform branch
                gload_lds16(BT + (size_t)(n0 + srow) * ldb + kbase + kt + s * 32 + gkb * 8,
                            &sB[bufi][s][w * 512]);
        }
    };

    stage(0, 0);
    __syncthreads();

    int cur = 0;
    for (int tix = 0; tix < nt; tix++) {
        if (tix + 1 < nt) stage((tix + 1) << 6, cur ^ 1);

        #pragma unroll
        for (int s = 0; s < 2; s++) {
            bf16x8 af[2], bfr[2];
            #pragma unroll
            for (int i = 0; i < 2; i++) {
                int rowA = wm * 32 + i * 16 + rr;
                af[i] = *(const bf16x8*)(&sA[cur][s][rowA * 32 + ((q ^ ((rowA >> 1) & 3)) * 8)]);
            }
            #pragma unroll
            for (int j = 0; j < 2; j++) {
                int rowB = wn * 32 + j * 16 + rr;
                bfr[j] = *(const bf16x8*)(&sB[cur][s][rowB * 32 + ((q ^ ((rowB >> 1) & 3)) * 8)]);
            }
            #pragma unroll
            for (int i = 0; i < 2; i++)
                #pragma unroll
                for (int j = 0; j < 2; j++)
                    acc[i][j] = __builtin_amdgcn_mfma_f32_16x16x32_bf16(af[i], bfr[j], acc[i][j], 0, 0, 0);
        }

        __syncthreads();
        cur ^= 1;
    }

    #pragma unroll
    for (int i = 0; i < 2; i++) {
        #pragma unroll
        for (int j = 0; j < 2; j++) {
            int col = n0 + wn * 32 + j * 16 + rr;
            #pragma unroll
            for (int jj = 0; jj < 4; jj++) {
                int row = m0 + wm * 32 + i * 16 + q * 4 + jj;
                atomicAdd(&C[(size_t)row * N + col], acc[i][j][jj]);
            }
        }
    }
}

// ---------------------------------------------------------------------------
// Causal depthwise conv (K=4) + bias + SiLU, vectorized.
// ---------------------------------------------------------------------------
__global__ void conv_silu(const __bf16* __restrict__ x, const float* __restrict__ cwT,
                          const float* __restrict__ bias, __bf16* __restrict__ xcB) {
    int row = blockIdx.x;          // 0..M_-1
    int d   = threadIdx.x * 8;     // 0..DM-8
    int l   = row % L_;
    size_t base = (size_t)row * DM + d;

    float acc[8];
    {
        const f32x4* b4 = (const f32x4*)(bias + d);
        f32x4 b0 = b4[0], b1 = b4[1];
        #pragma unroll
        for (int q = 0; q < 4; q++) { acc[q] = b0[q]; acc[4 + q] = b1[q]; }
    }
    #pragma unroll
    for (int i = 0; i < KC; i++) {
        int li = l - (KC - 1) + i;
        if (li >= 0) {                       // uniform across block
            bf16x8 xv = *(const bf16x8*)(x + base + (size_t)(i - (KC - 1)) * DM);
            const f32x4* w4 = (const f32x4*)(cwT + (size_t)i * DM + d);
            f32x4 w0 = w4[0], w1 = w4[1];
            #pragma unroll
            for (int q = 0; q < 4; q++) {
                acc[q]     = fmaf((float)xv[q],     w0[q], acc[q]);
                acc[4 + q] = fmaf((float)xv[4 + q], w1[q], acc[4 + q]);
            }
        }
    }
    bf16x8 out;
    #pragma unroll
    for (int q = 0; q < 8; q++) {
        float v = acc[q] / (1.f + __expf(-acc[q]));
        out[q] = (__bf16)v;
    }
    *(bf16x8*)(xcB + base) = out;
}

// ---------------------------------------------------------------------------
// Chunked scan, phase 1. Thread owns one (b, dm, chunk): 16 ds states in regs.
// ---------------------------------------------------------------------------
__global__ void scan_phase1(const __bf16* __restrict__ delta, const __bf16* __restrict__ xc,
                            const float* __restrict__ Bp, const float* __restrict__ A_log,
                            __bf16* __restrict__ aprodB, __bf16* __restrict__ cendB) {
    int blk = blockIdx.x;
    int c   = blk % NC;
    int rem = blk / NC;
    int dmt = rem % (DM / 256);
    int b   = rem / (DM / 256);
    int t   = threadIdx.x;
    int dm  = dmt * 256 + t;
    int l0  = c * CL;

    __shared__ float sB[CL * DS];      // 2 KB
    sB[t]       = Bp[((size_t)b * L_ + l0) * DS + t];
    sB[t + 256] = Bp[((size_t)b * L_ + l0) * DS + t + 256];
    __syncthreads();

    float Aval[DS];
    {
        const f32x4* Ap = (const f32x4*)(A_log + (size_t)dm * DS);
        #pragma unroll
        for (int r4 = 0; r4 < 4; r4++) {
            f32x4 a = Ap[r4];
            #pragma unroll
            for (int q = 0; q < 4; q++) Aval[r4 * 4 + q] = -__expf(a[q]);
        }
    }

    float h[DS], ap[DS];
    #pragma unroll
    for (int i = 0; i < DS; i++) { h[i] = 0.f; ap[i] = 1.f; }

    size_t base = ((size_t)b * L_ + l0) * DM + dm;
    #pragma unroll 4
    for (int j = 0; j < CL; j++) {
        float dl  = (float)delta[base + (size_t)j * DM];
        float xv  = (float)xc[base + (size_t)j * DM];
        float cmn = dl * xv;
        const f32x4* sB4 = (const f32x4*)(sB + j * DS);
        #pragma unroll
        for (int r4 = 0; r4 < 4; r4++) {
            f32x4 bv = sB4[r4];
            #pragma unroll
            for (int q = 0; q < 4; q++) {
                int i = r4 * 4 + q;
                float dA = __expf(dl * Aval[i]);
                ap[i] *= dA;
                h[i] = fmaf(dA, h[i], cmn * bv[q]);
            }
        }
    }

    size_t s = ((size_t)(b * DM + dm)) * DS;
    #pragma unroll
    for (int r8 = 0; r8 < 2; r8++) {
        bf16x8 va, vh;
        #pragma unroll
        for (int q = 0; q < 8; q++) { va[q] = (__bf16)ap[r8 * 8 + q]; vh[q] = (__bf16)h[r8 * 8 + q]; }
        ((bf16x8*)(aprodB + (size_t)c * S_ + s))[r8] = va;
        ((bf16x8*)(cendB  + (size_t)c * S_ + s))[r8] = vh;
    }
}

// ---------------------------------------------------------------------------
// Chunked scan, phase 2: scan chunk summaries (bf16 in/out, f32 math).
// One thread per state: 65536 threads = 1024 waves; fully coalesced.
// ---------------------------------------------------------------------------
__global__ void scan_phase2(const __bf16* __restrict__ aprodB, const __bf16* __restrict__ cendB,
                            __bf16* __restrict__ hinitB) {
    int u = blockIdx.x * 256 + threadIdx.x;   // 0..S_-1
    float h = 0.f;
    #pragma unroll
    for (int c = 0; c < NC; c++) {
        float a  = (float)aprodB[(size_t)c * S_ + u];
        float ce = (float)cendB [(size_t)c * S_ + u];
        hinitB[(size_t)c * S_ + u] = (__bf16)h;
        h = fmaf(a, h, ce);
    }
}

// ---------------------------------------------------------------------------
// Chunked scan, phase 3: replay from h_init, fused epilogue -> bf16.
// ---------------------------------------------------------------------------
__global__ void scan_phase3(const __bf16* __restrict__ delta, const __bf16* __restrict__ xc,
                            const float* __restrict__ Bp, const float* __restrict__ Cp,
                            const __bf16* __restrict__ res, const float* __restrict__ A_log,
                            const float* __restrict__ Dw, const __bf16* __restrict__ hinitB,
                            __bf16* __restrict__ ybar) {
    int blk = blockIdx.x;
    int c   = blk % NC;
    int rem = blk / NC;
    int dmt = rem % (DM / 256);
    int b   = rem / (DM / 256);
    int t   = threadIdx.x;
    int dm  = dmt * 256 + t;
    int l0  = c * CL;

    __shared__ float sB[CL * DS];      // 2 KB
    __shared__ float sC[CL * DS];      // 2 KB
    sB[t]       = Bp[((size_t)b * L_ + l0) * DS + t];
    sB[t + 256] = Bp[((size_t)b * L_ + l0) * DS + t + 256];
    sC[t]       = Cp[((size_t)b * L_ + l0) * DS + t];
    sC[t + 256] = Cp[((size_t)b * L_ + l0) * DS + t + 256];
    __syncthreads();

    float Aval[DS];
    {
        const f32x4* Ap = (const f32x4*)(A_log + (size_t)dm * DS);
        #pragma unroll
        for (int r4 = 0; r4 < 4; r4++) {
            f32x4 a = Ap[r4];
            #pragma unroll
            for (int q = 0; q < 4; q++) Aval[r4 * 4 + q] = -__expf(a[q]);
        }
    }
    float Dval = Dw[dm];

    float h[DS];
    {
        size_t s = ((size_t)(b * DM + dm)) * DS;
        #pragma unroll
        for (int r8 = 0; r8 < 2; r8++) {
            bf16x8 v = ((const bf16x8*)(hinitB + (size_t)c * S_ + s))[r8];
            #pragma unroll
            for (int q = 0; q < 8; q++) h[r8 * 8 + q] = (float)v[q];
        }
    }

    size_t base = ((size_t)b * L_ + l0) * DM + dm;
    #pragma unroll 4
    for (int j = 0; j < CL; j++) {
        float dl  = (float)delta[base + (size_t)j * DM];
        float xv  = (float)xc[base + (size_t)j * DM];
        float rv  = (float)res[base + (size_t)j * DM];
        float cmn = dl * xv;
        float y = 0.f;
        const f32x4* sB4 = (const f32x4*)(sB + j * DS);
        const f32x4* sC4 = (const f32x4*)(sC + j * DS);
        #pragma unroll
        for (int r4 = 0; r4 < 4; r4++) {
            f32x4 bv = sB4[r4];
            f32x4 cv = sC4[r4];
            #pragma unroll
            for (int q = 0; q < 4; q++) {
                int i = r4 * 4 + q;
                float dA = __expf(dl * Aval[i]);
                h[i] = fmaf(dA, h[i], cmn * bv[q]);
                y = fmaf(h[i], cv[q], y);
            }
        }
        float g = rv / (1.f + __expf(-rv));
        ybar[base + (size_t)j * DM] = (__bf16)((y + Dval * xv) * g);
    }
}

// ---------------------------------------------------------------------------
extern "C" void kernel_launch(void* const* d_in, const int* in_sizes, int n_in,
                              void* d_out, int out_size, void* d_ws, size_t ws_size,
                              hipStream_t stream) {
    // All reference tensors are float32.
    const float* x_in   = (const float*)d_in[0];
    const float* W_in   = (const float*)d_in[1];
    const float* W_res  = (const float*)d_in[2];
    const float* W_out  = (const float*)d_in[3];
    const float* conv_w = (const float*)d_in[4];
    const float* conv_b = (const float*)d_in[5];
    const float* A_log  = (const float*)d_in[6];
    const float* Dw     = (const float*)d_in[7];
    const float* W_B    = (const float*)d_in[8];
    const float* W_C    = (const float*)d_in[9];
    const float* W_dt   = (const float*)d_in[10];
    const float* dt_w   = (const float*)d_in[11];
    const float* dt_b   = (const float*)d_in[12];

    // ---------------- Workspace layout ----------------
    float* ws_f = (float*)d_ws;
    float* Bp    = ws_f;                        // M_*DS f32
    float* Cp    = Bp + (size_t)M_ * DS;        // M_*DS f32
    float* cwT   = Cp + (size_t)M_ * DS;        // KC*DM f32
    __bf16* bf_base = (__bf16*)(cwT + (size_t)KC * DM);
    __bf16* ybar   = bf_base;                   // M_*DM
    __bf16* xinB   = ybar   + (size_t)M_ * DM;  // M_*DIN
    __bf16* WinT   = xinB   + (size_t)M_ * DIN; // DM*DIN } adjacent: fused (4096 x DIN) BT
    __bf16* WresT  = WinT   + (size_t)DM * DIN; // DM*DIN }
    __bf16* WoutT  = WresT  + (size_t)DM * DIN; // DIN*DM
    __bf16* xB     = WoutT  + (size_t)DIN * DM; // M_*DM (conv input, bf16)
    __bf16* xcB    = xB     + (size_t)M_ * DM;  // M_*DM
    __bf16* projW  = xcB    + (size_t)M_ * DM;  // NP2*DM
    __bf16* dtwT   = projW  + (size_t)NP2 * DM; // DM*DR
    __bf16* dtmpB  = dtwT   + (size_t)DM * DR;  // M_*DR
    __bf16* deltaB = dtmpB  + (size_t)M_ * DR;  // M_*DM
    __bf16* resB   = deltaB + (size_t)M_ * DM;  // M_*DM
    __bf16* aprodB = resB   + (size_t)M_ * DM;  // NC*S_
    __bf16* cendB  = aprodB + (size_t)NC * S_;  // NC*S_
    __bf16* hinitB = cendB  + (size_t)NC * S_;  // NC*S_
    __bf16* PpartB = hinitB + (size_t)NC * S_;  // KSLICES*M_*NPC (compact bf16 partials)

    // ---------------- fused operand prep (1 launch) ----------------
    // +2048 blocks zero d_out for the K-split atomic out-GEMM
    prep_all<<<18720, 256, 0, stream>>>(x_in, W_in, W_res, W_out, dt_w, W_B, W_C, W_dt,
                                        conv_w, xinB, WinT, WresT, WoutT, dtwT, projW,
                                        cwT, (float*)d_out);

    // Fused input GEMMs: [x (bf16) | res (bf16)] = x_in @ [W_in | W_res]
    gemm_tile128<2><<<dim3((2 * DM) / 128, M_ / 128, 1), 1024, 0, stream>>>(
        xinB, WinT, (float*)xB, resB, nullptr, M_, 2 * DM, DIN, DIN, DIN);

    conv_silu<<<M_, 256, 0, stream>>>(xB, cwT, conv_b, xcB);

    // Packed projections, split-K -> compact bf16 partials (stride NPC)
    gemm_tile128<4><<<dim3(NP2 / 128, M_ / 128, KSLICES), 1024, 0, stream>>>(
        xcB, projW, nullptr, PpartB, nullptr, M_, NP2, KSL, DM, DM);
    reduce_split<<<(M_ * NPC) / 256, 256, 0, stream>>>(PpartB, Bp, Cp, dtmpB);

    // delta = softplus(dtmp @ dt_w + dt_b) -> bf16  (M_ x DM, K=DR)
    gemm_tile128<1><<<dim3(DM / 128, M_ / 128, 1), 1024, 0, stream>>>(
        dtmpB, dtwT, nullptr, deltaB, dt_b, M_, DM, DR, DR, DR);

    // Chunked selective scan (3 launches; kernel boundary = cheap barrier)
    int nblk = B_ * (DM / 256) * NC;   // 512
    scan_phase1<<<nblk, 256, 0, stream>>>(deltaB, xcB, Bp, A_log, aprodB, cendB);
    scan_phase2<<<S_ / 256, 256, 0, stream>>>(aprodB, cendB, hinitB);
    scan_phase3<<<nblk, 256, 0, stream>>>(deltaB, xcB, Bp, Cp, resB, A_log, Dw, hinitB, ybar);

    // out = ybar @ W_out  (M_ x DIN, K=DM), K-split-2 + atomicAdd, 512 blocks
    gemm_out64<<<dim3(DIN / 64, M_ / 128, 2), 512, 0, stream>>>(
        ybar, WoutT, (float*)d_out, M_, DIN, DM, DM, DM);
}

// Round 9
// 241.973 us; speedup vs baseline: 1.0460x; 1.0142x over previous
//
#include <hip/hip_runtime.h>
#include <hip/hip_bf16.h>

// Problem constants
constexpr int B_  = 2;
constexpr int L_  = 1024;
constexpr int DIN = 1024;
constexpr int DM  = 2048;
constexpr int DS  = 16;
constexpr int DR  = 128;
constexpr int KC  = 4;       // conv kernel size
constexpr int M_  = B_ * L_; // 2048 rows
constexpr int NP2 = 256;     // packed projection width (16+16+128 padded to 256)
constexpr int NPC = 160;     // compact packed width (16+16+128)
constexpr int KSLICES = 8;   // split-K for proj GEMM (K slice = 256)
constexpr int KSL = DM / KSLICES;     // 256

// Chunked scan parameters
constexpr int NC = 32;               // number of chunks
constexpr int CL = L_ / NC;          // chunk length (32)
constexpr int S_ = B_ * DM * DS;     // 65536 scan states

typedef __bf16 bf16x8 __attribute__((ext_vector_type(8)));
typedef __bf16 bf16x4 __attribute__((ext_vector_type(4)));
typedef float  f32x4  __attribute__((ext_vector_type(4)));

// ---------------------------------------------------------------------------
// async global->LDS 16B copy (global_load_lds_dwordx4).
// LDS dest must be wave-uniform base; HW adds lane*16.
// ---------------------------------------------------------------------------
__device__ __forceinline__ void gload_lds16(const void* g, void* l) {
    __builtin_amdgcn_global_load_lds(
        (const __attribute__((address_space(1))) void*)g,
        (__attribute__((address_space(3))) void*)l, 16, 0, 0);
}

// ---------------------------------------------------------------------------
// Fused operand prep (one launch): convert (vec4) + 4 transposes + proj pack +
// conv-weight transpose + d_out zero (for gemm_out K-split atomics).
// ---------------------------------------------------------------------------
__device__ __forceinline__ void transpose_block(const float* __restrict__ in,
                                                __bf16* __restrict__ out,
                                                int R, int C, int bx, int by, int t) {
    __shared__ float tile[32][33];
    int tx = t & 31, ty = t >> 5;   // (32, 8)
    #pragma unroll
    for (int j = 0; j < 32; j += 8)
        tile[ty + j][tx] = in[(size_t)(by * 32 + ty + j) * C + (bx * 32 + tx)];
    __syncthreads();
    #pragma unroll
    for (int j = 0; j < 32; j += 8)
        out[(size_t)(bx * 32 + ty + j) * R + (by * 32 + tx)] = (__bf16)tile[tx][ty + j];
}

__global__ void prep_all(const float* __restrict__ x_in, const float* __restrict__ W_in,
                         const float* __restrict__ W_res, const float* __restrict__ W_out,
                         const float* __restrict__ dt_w,
                         const float* __restrict__ W_B, const float* __restrict__ W_C,
                         const float* __restrict__ W_dt, const float* __restrict__ conv_w,
                         __bf16* __restrict__ xinB, __bf16* __restrict__ WinT,
                         __bf16* __restrict__ WresT, __bf16* __restrict__ WoutT,
                         __bf16* __restrict__ dtwT, __bf16* __restrict__ projW,
                         float* __restrict__ cwT, float* __restrict__ outz) {
    int blk = blockIdx.x, t = threadIdx.x;
    if (blk < 2048) {
        // x_in f32 -> bf16, vectorized x4 (2048*256*4 = M_*DIN elems)
        int i4 = blk * 256 + t;
        f32x4 v = ((const f32x4*)x_in)[i4];
        bf16x4 o;
        #pragma unroll
        for (int q = 0; q < 4; q++) o[q] = (__bf16)v[q];
        ((bf16x4*)xinB)[i4] = o;
    } else if (blk < 4096) {
        int b = blk - 2048;                       // grid (64, 32)
        transpose_block(W_in, WinT, DIN, DM, b % 64, b / 64, t);
    } else if (blk < 6144) {
        int b = blk - 4096;
        transpose_block(W_res, WresT, DIN, DM, b % 64, b / 64, t);
    } else if (blk < 8192) {
        int b = blk - 6144;                       // grid (32, 64)
        transpose_block(W_out, WoutT, DM, DIN, b % 32, b / 32, t);
    } else if (blk < 8448) {
        int b = blk - 8192;                       // grid (64, 4)
        transpose_block(dt_w, dtwT, DR, DM, b % 64, b / 64, t);
    } else if (blk < 10496) {
        int i = (blk - 8448) * 256 + t;           // 0 .. NP2*DM
        int k = i % DM;
        int n = i / DM;
        float v = 0.f;
        if (n < 16)        v = W_B[(size_t)k * DS + n];
        else if (n < 32)   v = W_C[(size_t)k * DS + (n - 16)];
        else if (n < 160)  v = W_dt[(size_t)k * DR + (n - 32)];
        projW[i] = (__bf16)v;
    } else if (blk < 10528) {
        int j = (blk - 10496) * 256 + t;          // 0 .. KC*DM
        int tap = j / DM, d = j % DM;
        cwT[j] = conv_w[d * KC + tap];
    } else {
        // zero d_out (M_*DIN f32) for the K-split atomic out-GEMM
        int i = (blk - 10528) * 256 + t;          // 0 .. M_*DIN/4
        ((f32x4*)outz)[i] = f32x4{0.f, 0.f, 0.f, 0.f};
    }
}

// ---------------------------------------------------------------------------
// Reduce proj split-K bf16 partials (dense stride NPC) and route:
// Bp, Cp (f32), dtmp (bf16). Fully coalesced.
// ---------------------------------------------------------------------------
__global__ void reduce_split(const __bf16* __restrict__ PpartB, float* __restrict__ Bp,
                             float* __restrict__ Cp, __bf16* __restrict__ dtmpB) {
    int i = blockIdx.x * 256 + threadIdx.x;   // 0 .. M_*NPC
    int row = i / NPC, c = i % NPC;
    float v = 0.f;
    #pragma unroll
    for (int ks = 0; ks < KSLICES; ks++)
        v += (float)PpartB[(size_t)ks * M_ * NPC + i];
    if (c < 16)       Bp[(size_t)row * DS + c] = v;
    else if (c < 32)  Cp[(size_t)row * DS + (c - 16)] = v;
    else              dtmpB[(size_t)row * DR + (c - 32)] = (__bf16)v;
}

// ---------------------------------------------------------------------------
// FUSED input GEMM + causal depthwise conv + SiLU.
// Block tile 128x128 over N=4096 ([x | res]), 1024 thr = 16 waves (4x4 of
// 32x32), BK=64 two-half staging (R7-proven). NEW: for x-half blocks, the
// 3-row causal halo (rows m0-3..m0-1) is RECOMPUTED via one extra 16-row
// MFMA fragment per wm==0 wave (B fragments reused from the main loop; halo
// A fragments stream from global with 1-tile prefetch). Epilogue writes the
// x tile + halo to LDS (stride 136 = conflict-free) and applies
// conv(K=4)+bias+SiLU in-place -> xcB. Numerically identical to the old
// separate conv_silu (same bf16 x, same fma order). res blocks: plain store.
// __launch_bounds__(1024,4): halo regs (~+20 VGPR) would spill at the old
// (,8)/64-VGPR cap; 16 waves/CU costs <=2-4us (R4 evidence), spill costs more.
// ---------------------------------------------------------------------------
__global__ __launch_bounds__(1024, 4)
void gemm_in_conv(const __bf16* __restrict__ A, const __bf16* __restrict__ BT,
                  __bf16* __restrict__ xcB, __bf16* __restrict__ resB,
                  const float* __restrict__ cwT, const float* __restrict__ conv_b) {
    __shared__ __bf16 smem[32768];   // 64 KB: [sA 16K elems | sB 16K elems]; reused as sX
    const int lda = DIN, ldb = DIN, K = DIN;
    int t = threadIdx.x;
    int lane = t & 63, w = t >> 6;          // 16 waves
    int wm = w >> 2, wn = w & 3;            // 4(M) x 4(N): 32x32 each
    int m0 = blockIdx.y * 128, n0 = blockIdx.x * 128;
    int q = lane >> 4, rr = lane & 15;
    bool is_x = (n0 < DM);
    bool has_halo = is_x && ((m0 & (L_ - 1)) != 0);   // l0 != 0 within batch

    f32x4 acc[2][2] = {};
    f32x4 hacc[2] = {};     // halo 16x32 per wm==0 wave (only rows 13..15 used)

    const int nt = K >> 6;

    int t2 = t & 511;
    int srow = t2 >> 2;         // 0..127
    int slot = t2 & 3;
    int gkb = slot ^ ((srow >> 1) & 3);

    auto SA = [&](int buf, int s) { return smem + (buf * 2 + s) * 4096; };
    auto SB = [&](int buf, int s) { return smem + 16384 + (buf * 2 + s) * 4096; };

    auto stage = [&](int kt, int bufi) {
        if (t < 512) {
            #pragma unroll
            for (int s = 0; s < 2; s++)
                gload_lds16(A + (size_t)(m0 + srow) * lda + kt + s * 32 + gkb * 8,
                            SA(bufi, s) + w * 512);
        } else {
            #pragma unroll
            for (int s = 0; s < 2; s++)
                gload_lds16(BT + (size_t)(n0 + srow) * ldb + kt + s * 32 + gkb * 8,
                            SB(bufi, s) + (w - 8) * 512);
        }
    };

    // halo A-fragment prefetch (wm==0 waves): row rr of halo tile m0-16..m0-1,
    // k-chunk q*8 — same fragment mapping the LDS path produces.
    bf16x8 ah[2];
    if (wm == 0 && has_halo) {
        #pragma unroll
        for (int s = 0; s < 2; s++)
            ah[s] = *(const bf16x8*)(A + (size_t)(m0 - 16 + rr) * lda + s * 32 + q * 8);
    }

    stage(0, 0);
    __syncthreads();   // tile 0 resident

    int cur = 0;
    for (int tix = 0; tix < nt; tix++) {
        if (tix + 1 < nt) stage((tix + 1) << 6, cur ^ 1);

        bf16x8 ahn[2];
        if (wm == 0 && has_halo && tix + 1 < nt) {
            int ktn = (tix + 1) << 6;
            #pragma unroll
            for (int s = 0; s < 2; s++)
                ahn[s] = *(const bf16x8*)(A + (size_t)(m0 - 16 + rr) * lda + ktn + s * 32 + q * 8);
        }

        #pragma unroll
        for (int s = 0; s < 2; s++) {
            bf16x8 af[2], bfr[2];
            #pragma unroll
            for (int i = 0; i < 2; i++) {
                int rowA = wm * 32 + i * 16 + rr;
                af[i] = *(const bf16x8*)(SA(cur, s) + rowA * 32 + ((q ^ ((rowA >> 1) & 3)) * 8));
            }
            #pragma unroll
            for (int j = 0; j < 2; j++) {
                int rowB = wn * 32 + j * 16 + rr;
                bfr[j] = *(const bf16x8*)(SB(cur, s) + rowB * 32 + ((q ^ ((rowB >> 1) & 3)) * 8));
            }
            #pragma unroll
            for (int i = 0; i < 2; i++)
                #pragma unroll
                for (int j = 0; j < 2; j++)
                    acc[i][j] = __builtin_amdgcn_mfma_f32_16x16x32_bf16(af[i], bfr[j], acc[i][j], 0, 0, 0);
            if (wm == 0 && has_halo) {
                hacc[0] = __builtin_amdgcn_mfma_f32_16x16x32_bf16(ah[s], bfr[0], hacc[0], 0, 0, 0);
                hacc[1] = __builtin_amdgcn_mfma_f32_16x16x32_bf16(ah[s], bfr[1], hacc[1], 0, 0, 0);
            }
        }
        if (wm == 0 && has_halo && tix + 1 < nt) { ah[0] = ahn[0]; ah[1] = ahn[1]; }

        __syncthreads();   // drains vmcnt (next tile resident) + lgkm; WAR safe
        cur ^= 1;
    }

    if (!is_x) {
        // res half: plain bf16 store
        #pragma unroll
        for (int i = 0; i < 2; i++) {
            #pragma unroll
            for (int j = 0; j < 2; j++) {
                int col = (n0 - DM) + wn * 32 + j * 16 + rr;
                #pragma unroll
                for (int jj = 0; jj < 4; jj++) {
                    int row = m0 + wm * 32 + i * 16 + q * 4 + jj;
                    resB[(size_t)row * DM + col] = (__bf16)acc[i][j][jj];
                }
            }
        }
        return;
    }

    // ---- x half: stage x tile (+3-row halo) into LDS, conv+SiLU, store xc ----
    constexpr int XS = 136;   // row stride (elems): 272B -> de-conflicted writes
    // rows of sX: 0..2 = x[m0-3..m0-1] (halo or zero), 3+k = x[m0+k]
    #pragma unroll
    for (int i = 0; i < 2; i++)
        #pragma unroll
        for (int j = 0; j < 2; j++) {
            int cc = wn * 32 + j * 16 + rr;
            #pragma unroll
            for (int jj = 0; jj < 4; jj++) {
                int r = wm * 32 + i * 16 + q * 4 + jj;
                smem[(r + 3) * XS + cc] = (__bf16)acc[i][j][jj];
            }
        }
    if (wm == 0) {
        #pragma unroll
        for (int j = 0; j < 2; j++) {
            int cc = wn * 32 + j * 16 + rr;
            #pragma unroll
            for (int jj = 0; jj < 4; jj++) {
                int r = q * 4 + jj;          // halo tile row 0..15; rows 13..15 -> sX 0..2
                if (r >= 13)
                    smem[(r - 13) * XS + cc] = has_halo ? (__bf16)hacc[j][jj] : (__bf16)0.f;
            }
        }
    }
    __syncthreads();

    {
        int c  = t & 127;          // local col
        int rg = t >> 7;           // 0..7: rows rg*16 .. +15
        int d  = n0 + c;           // global x col (< DM)
        float w0 = cwT[0 * DM + d], w1 = cwT[1 * DM + d];
        float w2 = cwT[2 * DM + d], w3 = cwT[3 * DM + d];
        float bv = conv_b[d];
        float x0 = (float)smem[(rg * 16 + 0) * XS + c];
        float x1 = (float)smem[(rg * 16 + 1) * XS + c];
        float x2 = (float)smem[(rg * 16 + 2) * XS + c];
        #pragma unroll
        for (int k = 0; k < 16; k++) {
            float x3 = (float)smem[(rg * 16 + k + 3) * XS + c];
            float v = fmaf(x3, w3, fmaf(x2, w2, fmaf(x1, w1, fmaf(x0, w0, bv))));
            float sv = v / (1.f + __expf(-v));
            xcB[(size_t)(m0 + rg * 16 + k) * DM + d] = (__bf16)sv;
            x0 = x1; x1 = x2; x2 = x3;
        }
    }
}

// ---------------------------------------------------------------------------
// MFMA GEMM (proj/delta): 128x128 block tile, BK=64 two halves, dbuf 2-phase,
// 1024 thr = 16 waves (4x4 of 32x32); waves 0-7 stage A, 8-15 stage B.
// R7-proven verbatim.
// EPI: 1 = +bias[col], softplus -> bf16 Cb (stride N);
//      4 = compact bf16 partial: col<NPC -> Cb + z*M*NPC, stride NPC.
// ---------------------------------------------------------------------------
template<int EPI>
__global__ __launch_bounds__(1024, 8)
void gemm_tile128(const __bf16* __restrict__ A, const __bf16* __restrict__ BT,
                  __bf16* __restrict__ Cb, const float* __restrict__ bias,
                  int M, int N, int K, int lda, int ldb) {
    __shared__ __bf16 sA[2][2][128 * 32];   // 16 KB
    __shared__ __bf16 sB[2][2][128 * 32];   // 16 KB
    int t = threadIdx.x;
    int lane = t & 63, w = t >> 6;          // 16 waves
    int wm = w >> 2, wn = w & 3;            // 4(M) x 4(N): 32x32 each
    int m0 = blockIdx.y * 128, n0 = blockIdx.x * 128;
    int kbase = blockIdx.z * K;
    int q = lane >> 4, rr = lane & 15;

    f32x4 acc[2][2] = {};

    const int nt = K >> 6;

    int t2 = t & 511;
    int srow = t2 >> 2;         // 0..127
    int slot = t2 & 3;
    int gkb = slot ^ ((srow >> 1) & 3);

    auto stage = [&](int kt, int bufi) {
        if (t < 512) {
            #pragma unroll
            for (int s = 0; s < 2; s++)
                gload_lds16(A + (size_t)(m0 + srow) * lda + kbase + kt + s * 32 + gkb * 8,
                            &sA[bufi][s][w * 512]);
        } else {
            #pragma unroll
            for (int s = 0; s < 2; s++)
                gload_lds16(BT + (size_t)(n0 + srow) * ldb + kbase + kt + s * 32 + gkb * 8,
                            &sB[bufi][s][(w - 8) * 512]);
        }
    };

    stage(0, 0);
    __syncthreads();   // tile 0 resident

    int cur = 0;
    for (int tix = 0; tix < nt; tix++) {
        if (tix + 1 < nt) stage((tix + 1) << 6, cur ^ 1);

        #pragma unroll
        for (int s = 0; s < 2; s++) {
            bf16x8 af[2], bfr[2];
            #pragma unroll
            for (int i = 0; i < 2; i++) {
                int rowA = wm * 32 + i * 16 + rr;
                af[i] = *(const bf16x8*)(&sA[cur][s][rowA * 32 + ((q ^ ((rowA >> 1) & 3)) * 8)]);
            }
            #pragma unroll
            for (int j = 0; j < 2; j++) {
                int rowB = wn * 32 + j * 16 + rr;
                bfr[j] = *(const bf16x8*)(&sB[cur][s][rowB * 32 + ((q ^ ((rowB >> 1) & 3)) * 8)]);
            }
            #pragma unroll
            for (int i = 0; i < 2; i++)
                #pragma unroll
                for (int j = 0; j < 2; j++)
                    acc[i][j] = __builtin_amdgcn_mfma_f32_16x16x32_bf16(af[i], bfr[j], acc[i][j], 0, 0, 0);
        }

        __syncthreads();   // drains vmcnt (next tile resident) + lgkm; WAR safe
        cur ^= 1;
    }

    #pragma unroll
    for (int i = 0; i < 2; i++) {
        #pragma unroll
        for (int j = 0; j < 2; j++) {
            int col = n0 + wn * 32 + j * 16 + rr;
            #pragma unroll
            for (int jj = 0; jj < 4; jj++) {
                int row = m0 + wm * 32 + i * 16 + q * 4 + jj;
                float v = acc[i][j][jj];
                if (EPI == 1) {
                    float z = v + bias[col];
                    Cb[(size_t)row * N + col] = (__bf16)((z > 20.f) ? z : log1pf(__expf(z)));
                } else {
                    if (col < NPC)
                        Cb[(size_t)blockIdx.z * M * NPC + (size_t)row * NPC + col] = (__bf16)v;
                }
            }
        }
    }
}

// ---------------------------------------------------------------------------
// Out GEMM: 128(M)x64(N) tile, 8 waves (512 thr) each 32x32; block-level
// K-split-2 (blockIdx.z) + f32 atomicAdd epilogue (d_out zeroed in prep_all).
// R7-proven verbatim.
// ---------------------------------------------------------------------------
__global__ void gemm_out64(const __bf16* __restrict__ A, const __bf16* __restrict__ BT,
                           float* __restrict__ C, int M, int N, int K, int lda, int ldb) {
    __shared__ __bf16 sA[2][2][128 * 32];   // 32 KB
    __shared__ __bf16 sB[2][2][64 * 32];    // 16 KB
    int t = threadIdx.x;
    int lane = t & 63, w = t >> 6;        // 8 waves
    int wm = w >> 1, wn = w & 1;          // 4(M) x 2(N): 32x32 each
    int m0 = blockIdx.y * 128, n0 = blockIdx.x * 64;
    int kh = K >> 1;
    int kbase = blockIdx.z * kh;
    int q = lane >> 4, rr = lane & 15;

    f32x4 acc[2][2] = {};
    int srow = t >> 2;          // 0..127
    int slot = t & 3;

    const int nt = kh >> 6;

    auto stage = [&](int kt, int bufi) {
        int gkb = slot ^ ((srow >> 1) & 3);
        #pragma unroll
        for (int s = 0; s < 2; s++) {
            gload_lds16(A + (size_t)(m0 + srow) * lda + kbase + kt + s * 32 + gkb * 8,
                        &sA[bufi][s][w * 512]);
            if (t < 256)   // waves 0-3 stage B (64 rows); wave-uniform branch
                gload_lds16(BT + (size_t)(n0 + srow) * ldb + kbase + kt + s * 32 + gkb * 8,
                            &sB[bufi][s][w * 512]);
        }
    };

    stage(0, 0);
    __syncthreads();

    int cur = 0;
    for (int tix = 0; tix < nt; tix++) {
        if (tix + 1 < nt) stage((tix + 1) << 6, cur ^ 1);

        #pragma unroll
        for (int s = 0; s < 2; s++) {
            bf16x8 af[2], bfr[2];
            #pragma unroll
            for (int i = 0; i < 2; i++) {
                int rowA = wm * 32 + i * 16 + rr;
                af[i] = *(const bf16x8*)(&sA[cur][s][rowA * 32 + ((q ^ ((rowA >> 1) & 3)) * 8)]);
            }
            #pragma unroll
            for (int j = 0; j < 2; j++) {
                int rowB = wn * 32 + j * 16 + rr;
                bfr[j] = *(const bf16x8*)(&sB[cur][s][rowB * 32 + ((q ^ ((rowB >> 1) & 3)) * 8)]);
            }
            #pragma unroll
            for (int i = 0; i < 2; i++)
                #pragma unroll
                for (int j = 0; j < 2; j++)
                    acc[i][j] = __builtin_amdgcn_mfma_f32_16x16x32_bf16(af[i], bfr[j], acc[i][j], 0, 0, 0);
        }

        __syncthreads();
        cur ^= 1;
    }

    #pragma unroll
    for (int i = 0; i < 2; i++) {
        #pragma unroll
        for (int j = 0; j < 2; j++) {
            int col = n0 + wn * 32 + j * 16 + rr;
            #pragma unroll
            for (int jj = 0; jj < 4; jj++) {
                int row = m0 + wm * 32 + i * 16 + q * 4 + jj;
                atomicAdd(&C[(size_t)row * N + col], acc[i][j][jj]);
            }
        }
    }
}

// ---------------------------------------------------------------------------
// Chunked scan, phase 1. Thread owns one (b, dm, chunk): 16 ds states in regs.
// ---------------------------------------------------------------------------
__global__ void scan_phase1(const __bf16* __restrict__ delta, const __bf16* __restrict__ xc,
                            const float* __restrict__ Bp, const float* __restrict__ A_log,
                            __bf16* __restrict__ aprodB, __bf16* __restrict__ cendB) {
    int blk = blockIdx.x;
    int c   = blk % NC;
    int rem = blk / NC;
    int dmt = rem % (DM / 256);
    int b   = rem / (DM / 256);
    int t   = threadIdx.x;
    int dm  = dmt * 256 + t;
    int l0  = c * CL;

    __shared__ float sB[CL * DS];      // 2 KB
    sB[t]       = Bp[((size_t)b * L_ + l0) * DS + t];
    sB[t + 256] = Bp[((size_t)b * L_ + l0) * DS + t + 256];
    __syncthreads();

    float Aval[DS];
    {
        const f32x4* Ap = (const f32x4*)(A_log + (size_t)dm * DS);
        #pragma unroll
        for (int r4 = 0; r4 < 4; r4++) {
            f32x4 a = Ap[r4];
            #pragma unroll
            for (int q = 0; q < 4; q++) Aval[r4 * 4 + q] = -__expf(a[q]);
        }
    }

    float h[DS], ap[DS];
    #pragma unroll
    for (int i = 0; i < DS; i++) { h[i] = 0.f; ap[i] = 1.f; }

    size_t base = ((size_t)b * L_ + l0) * DM + dm;
    #pragma unroll 4
    for (int j = 0; j < CL; j++) {
        float dl  = (float)delta[base + (size_t)j * DM];
        float xv  = (float)xc[base + (size_t)j * DM];
        float cmn = dl * xv;
        const f32x4* sB4 = (const f32x4*)(sB + j * DS);
        #pragma unroll
        for (int r4 = 0; r4 < 4; r4++) {
            f32x4 bv = sB4[r4];
            #pragma unroll
            for (int q = 0; q < 4; q++) {
                int i = r4 * 4 + q;
                float dA = __expf(dl * Aval[i]);
                ap[i] *= dA;
                h[i] = fmaf(dA, h[i], cmn * bv[q]);
            }
        }
    }

    size_t s = ((size_t)(b * DM + dm)) * DS;
    #pragma unroll
    for (int r8 = 0; r8 < 2; r8++) {
        bf16x8 va, vh;
        #pragma unroll
        for (int q = 0; q < 8; q++) { va[q] = (__bf16)ap[r8 * 8 + q]; vh[q] = (__bf16)h[r8 * 8 + q]; }
        ((bf16x8*)(aprodB + (size_t)c * S_ + s))[r8] = va;
        ((bf16x8*)(cendB  + (size_t)c * S_ + s))[r8] = vh;
    }
}

// ---------------------------------------------------------------------------
// Chunked scan, phase 2: scan chunk summaries (bf16 in/out, f32 math).
// One thread per state: 65536 threads = 1024 waves; fully coalesced.
// ---------------------------------------------------------------------------
__global__ void scan_phase2(const __bf16* __restrict__ aprodB, const __bf16* __restrict__ cendB,
                            __bf16* __restrict__ hinitB) {
    int u = blockIdx.x * 256 + threadIdx.x;   // 0..S_-1
    float h = 0.f;
    #pragma unroll
    for (int c = 0; c < NC; c++) {
        float a  = (float)aprodB[(size_t)c * S_ + u];
        float ce = (float)cendB [(size_t)c * S_ + u];
        hinitB[(size_t)c * S_ + u] = (__bf16)h;
        h = fmaf(a, h, ce);
    }
}

// ---------------------------------------------------------------------------
// Chunked scan, phase 3: replay from h_init, fused epilogue -> bf16.
// ---------------------------------------------------------------------------
__global__ void scan_phase3(const __bf16* __restrict__ delta, const __bf16* __restrict__ xc,
                            const float* __restrict__ Bp, const float* __restrict__ Cp,
                            const __bf16* __restrict__ res, const float* __restrict__ A_log,
                            const float* __restrict__ Dw, const __bf16* __restrict__ hinitB,
                            __bf16* __restrict__ ybar) {
    int blk = blockIdx.x;
    int c   = blk % NC;
    int rem = blk / NC;
    int dmt = rem % (DM / 256);
    int b   = rem / (DM / 256);
    int t   = threadIdx.x;
    int dm  = dmt * 256 + t;
    int l0  = c * CL;

    __shared__ float sB[CL * DS];      // 2 KB
    __shared__ float sC[CL * DS];      // 2 KB
    sB[t]       = Bp[((size_t)b * L_ + l0) * DS + t];
    sB[t + 256] = Bp[((size_t)b * L_ + l0) * DS + t + 256];
    sC[t]       = Cp[((size_t)b * L_ + l0) * DS + t];
    sC[t + 256] = Cp[((size_t)b * L_ + l0) * DS + t + 256];
    __syncthreads();

    float Aval[DS];
    {
        const f32x4* Ap = (const f32x4*)(A_log + (size_t)dm * DS);
        #pragma unroll
        for (int r4 = 0; r4 < 4; r4++) {
            f32x4 a = Ap[r4];
            #pragma unroll
            for (int q = 0; q < 4; q++) Aval[r4 * 4 + q] = -__expf(a[q]);
        }
    }
    float Dval = Dw[dm];

    float h[DS];
    {
        size_t s = ((size_t)(b * DM + dm)) * DS;
        #pragma unroll
        for (int r8 = 0; r8 < 2; r8++) {
            bf16x8 v = ((const bf16x8*)(hinitB + (size_t)c * S_ + s))[r8];
            #pragma unroll
            for (int q = 0; q < 8; q++) h[r8 * 8 + q] = (float)v[q];
        }
    }

    size_t base = ((size_t)b * L_ + l0) * DM + dm;
    #pragma unroll 4
    for (int j = 0; j < CL; j++) {
        float dl  = (float)delta[base + (size_t)j * DM];
        float xv  = (float)xc[base + (size_t)j * DM];
        float rv  = (float)res[base + (size_t)j * DM];
        float cmn = dl * xv;
        float y = 0.f;
        const f32x4* sB4 = (const f32x4*)(sB + j * DS);
        const f32x4* sC4 = (const f32x4*)(sC + j * DS);
        #pragma unroll
        for (int r4 = 0; r4 < 4; r4++) {
            f32x4 bv = sB4[r4];
            f32x4 cv = sC4[r4];
            #pragma unroll
            for (int q = 0; q < 4; q++) {
                int i = r4 * 4 + q;
                float dA = __expf(dl * Aval[i]);
                h[i] = fmaf(dA, h[i], cmn * bv[q]);
                y = fmaf(h[i], cv[q], y);
            }
        }
        float g = rv / (1.f + __expf(-rv));
        ybar[base + (size_t)j * DM] = (__bf16)((y + Dval * xv) * g);
    }
}

// ---------------------------------------------------------------------------
extern "C" void kernel_launch(void* const* d_in, const int* in_sizes, int n_in,
                              void* d_out, int out_size, void* d_ws, size_t ws_size,
                              hipStream_t stream) {
    // All reference tensors are float32.
    const float* x_in   = (const float*)d_in[0];
    const float* W_in   = (const float*)d_in[1];
    const float* W_res  = (const float*)d_in[2];
    const float* W_out  = (const float*)d_in[3];
    const float* conv_w = (const float*)d_in[4];
    const float* conv_b = (const float*)d_in[5];
    const float* A_log  = (const float*)d_in[6];
    const float* Dw     = (const float*)d_in[7];
    const float* W_B    = (const float*)d_in[8];
    const float* W_C    = (const float*)d_in[9];
    const float* W_dt   = (const float*)d_in[10];
    const float* dt_w   = (const float*)d_in[11];
    const float* dt_b   = (const float*)d_in[12];

    // ---------------- Workspace layout (unchanged; xB slot now unused) -----
    float* ws_f = (float*)d_ws;
    float* Bp    = ws_f;                        // M_*DS f32
    float* Cp    = Bp + (size_t)M_ * DS;        // M_*DS f32
    float* cwT   = Cp + (size_t)M_ * DS;        // KC*DM f32
    __bf16* bf_base = (__bf16*)(cwT + (size_t)KC * DM);
    __bf16* ybar   = bf_base;                   // M_*DM
    __bf16* xinB   = ybar   + (size_t)M_ * DM;  // M_*DIN
    __bf16* WinT   = xinB   + (size_t)M_ * DIN; // DM*DIN } adjacent: fused (4096 x DIN) BT
    __bf16* WresT  = WinT   + (size_t)DM * DIN; // DM*DIN }
    __bf16* WoutT  = WresT  + (size_t)DM * DIN; // DIN*DM
    __bf16* xB     = WoutT  + (size_t)DIN * DM; // (unused)
    __bf16* xcB    = xB     + (size_t)M_ * DM;  // M_*DM (conv output)
    __bf16* projW  = xcB    + (size_t)M_ * DM;  // NP2*DM
    __bf16* dtwT   = projW  + (size_t)NP2 * DM; // DM*DR
    __bf16* dtmpB  = dtwT   + (size_t)DM * DR;  // M_*DR
    __bf16* deltaB = dtmpB  + (size_t)M_ * DR;  // M_*DM
    __bf16* resB   = deltaB + (size_t)M_ * DM;  // M_*DM
    __bf16* aprodB = resB   + (size_t)M_ * DM;  // NC*S_
    __bf16* cendB  = aprodB + (size_t)NC * S_;  // NC*S_
    __bf16* hinitB = cendB  + (size_t)NC * S_;  // NC*S_
    __bf16* PpartB = hinitB + (size_t)NC * S_;  // KSLICES*M_*NPC (compact bf16 partials)

    // ---------------- fused operand prep (1 launch) ----------------
    prep_all<<<12576, 256, 0, stream>>>(x_in, W_in, W_res, W_out, dt_w, W_B, W_C, W_dt,
                                        conv_w, xinB, WinT, WresT, WoutT, dtwT, projW,
                                        cwT, (float*)d_out);

    // Fused: [x | res] = x_in @ [W_in | W_res], + conv(K=4)+SiLU on x -> xcB
    gemm_in_conv<<<dim3((2 * DM) / 128, M_ / 128), 1024, 0, stream>>>(
        xinB, WinT, xcB, resB, cwT, conv_b);

    // Packed projections, split-K -> compact bf16 partials (stride NPC)
    gemm_tile128<4><<<dim3(NP2 / 128, M_ / 128, KSLICES), 1024, 0, stream>>>(
        xcB, projW, PpartB, nullptr, M_, NP2, KSL, DM, DM);
    reduce_split<<<(M_ * NPC) / 256, 256, 0, stream>>>(PpartB, Bp, Cp, dtmpB);

    // delta = softplus(dtmp @ dt_w + dt_b) -> bf16  (M_ x DM, K=DR)
    gemm_tile128<1><<<dim3(DM / 128, M_ / 128, 1), 1024, 0, stream>>>(
        dtmpB, dtwT, deltaB, dt_b, M_, DM, DR, DR, DR);

    // Chunked selective scan (3 launches; kernel boundary = cheap barrier)
    int nblk = B_ * (DM / 256) * NC;   // 512
    scan_phase1<<<nblk, 256, 0, stream>>>(deltaB, xcB, Bp, A_log, aprodB, cendB);
    scan_phase2<<<S_ / 256, 256, 0, stream>>>(aprodB, cendB, hinitB);
    scan_phase3<<<nblk, 256, 0, stream>>>(deltaB, xcB, Bp, Cp, resB, A_log, Dw, hinitB, ybar);

    // out = ybar @ W_out  (M_ x DIN, K=DM), K-split-2 + atomicAdd, 512 blocks
    gemm_out64<<<dim3(DIN / 64, M_ / 128, 2), 512, 0, stream>>>(
        ybar, WoutT, (float*)d_out, M_, DIN, DM, DM, DM);
}